// Round 5
// baseline (328.074 us; speedup 1.0000x reference)
//
#include <hip/hip_runtime.h>

#define BB 8
#define CC 64
#define HH 128
#define WW 128
#define TT 3
#define LL 4
#define MM 3
#define PADH 40   // halves per px in conv LDS tile (32 ch + 8 pad) -> 80 B stride

typedef _Float16 half8 __attribute__((ext_vector_type(8)));
typedef _Float16 half4 __attribute__((ext_vector_type(4)));
typedef float floatx16 __attribute__((ext_vector_type(16)));

// ---------------------------------------------------------------------------
// Routing chain (device helper): argmax over (a + g), chained on prev index.
// (log_softmax(a)+g)/tau is a monotone transform of (a+g). Cheap (24 floats),
// recomputed per block in prep_weights -- removes a dispatch + dependency.
// ---------------------------------------------------------------------------
__device__ inline void compute_sel(const float* __restrict__ alpha0,
                                   const float* __restrict__ alphas,
                                   const float* __restrict__ g0,
                                   const float* __restrict__ gs,
                                   int* sel_local) {
    for (int t = 0; t < TT; ++t) {
        int idx = 0;
        for (int layer = 0; layer < LL; ++layer) {
            const float *a, *g;
            if (layer == 0) { a = alpha0 + t * MM; g = g0 + t * MM; }
            else {
                int off = (((layer - 1) * TT + t) * MM + idx) * MM;
                a = alphas + off; g = gs + off;
            }
            float best = a[0] + g[0];
            int bi = 0;
            for (int j = 1; j < MM; ++j) {
                float v = a[j] + g[j];
                if (v > best) { best = v; bi = j; }
            }
            sel_local[t * LL + layer] = bi;
            idx = bi;
        }
    }
}

// ---------------------------------------------------------------------------
// Weight prep: route, gather selected modules, fp32 -> fp16, rearrange to
// A-frag order W3[tl][tap][c][il][o][lane*8] (one a-frag = 1 KB wave-load).
// Also emits packed bias table Bsel[tl][64].
// ---------------------------------------------------------------------------
__global__ __launch_bounds__(256) void prep_weights(
    const float* __restrict__ enc_w, // [L][M][64][64][3][3]
    const float* __restrict__ enc_b, // [L][M][64]
    const float* __restrict__ alpha0,
    const float* __restrict__ alphas,
    const float* __restrict__ g0,
    const float* __restrict__ gs,
    _Float16* __restrict__ W3,       // [12][36864]
    float* __restrict__ Bsel)        // [12][64]
{
    int sel_local[TT * LL];
    compute_sel(alpha0, alphas, g0, gs, sel_local);

    int tl = blockIdx.y;             // t*4 + layer
    int layer = tl & 3;
    int m = sel_local[tl];

    const float* src = enc_w + ((size_t)layer * MM + m) * (CC * CC * 9);
    _Float16* dst = W3 + (size_t)tl * 36864;
    for (int i = blockIdx.x * 256 + threadIdx.x; i < 36864; i += gridDim.x * 256) {
        int j   = i & 7;
        int l   = (i >> 3) & 63;
        int o   = (i >> 9) & 1;
        int il  = (i >> 10) & 1;
        int c   = (i >> 11) & 1;
        int tap = i >> 12;
        int oc  = o * 32 + (l & 31);
        int kch = c * 32 + il * 16 + (l >> 5) * 8 + j;
        dst[i] = (_Float16)src[(oc * CC + kch) * 9 + tap];
    }
    if (blockIdx.x == 0 && threadIdx.x < CC)
        Bsel[tl * CC + threadIdx.x] = enc_b[((size_t)layer * MM + m) * CC + threadIdx.x];
}

// ---------------------------------------------------------------------------
// x: NCHW fp32 -> NHWC f16. Lane = px (coalesced 256 B loads), LDS transpose.
// ---------------------------------------------------------------------------
__global__ __launch_bounds__(256) void to_nhwc(
    const float* __restrict__ x,    // [B][64][128][128]
    _Float16* __restrict__ act0)    // [B][128][128][64]
{
    const int xs = blockIdx.x;
    const int y  = blockIdx.y;
    const int b  = blockIdx.z;

    __shared__ _Float16 lds[64 * 72];

    const int wv = threadIdx.x >> 6;
    const int l  = threadIdx.x & 63;
    const float* src = x + ((size_t)b * CC * HH + y) * WW + xs * 64 + l;
#pragma unroll
    for (int k = 0; k < 16; ++k) {
        int ch = wv * 16 + k;
        lds[l * 72 + ch] = (_Float16)src[(size_t)ch * HH * WW];
    }
    __syncthreads();
    int px = threadIdx.x >> 2;
    int q  = threadIdx.x & 3;
    _Float16* dst = act0 + (((size_t)b * HH + y) * WW + xs * 64 + px) * CC + q * 16;
    *(half8*)dst       = *(const half8*)&lds[px * 72 + q * 16];
    *(half8*)(dst + 8) = *(const half8*)&lds[px * 72 + q * 16 + 8];
}

// ---------------------------------------------------------------------------
// Shared conv core: stages input, runs the 2-chunk x 9-tap MFMA loop.
// Block 256 thr / 4 waves: 4 output rows x 64 px x 64 oc (wave = one row).
// ---------------------------------------------------------------------------
#define CONV_CORE(inp, Wt)                                                         \
    floatx16 acc[2][2];                                                            \
    _Pragma("unroll") for (int o = 0; o < 2; ++o)                                  \
        _Pragma("unroll") for (int j = 0; j < 2; ++j)                              \
            _Pragma("unroll") for (int i = 0; i < 16; ++i) acc[o][j][i] = 0.f;     \
    half8 a_cur[4], a_nxt[4];                                                      \
    _Pragma("unroll") for (int o = 0; o < 2; ++o)                                  \
        _Pragma("unroll") for (int il = 0; il < 2; ++il)                           \
            a_cur[o * 2 + il] = WFRAG(0, 0, o, il);                                \
    for (int c = 0; c < 2; ++c) {                                                  \
        if (c) __syncthreads();                                                    \
        for (int i = tid; i < 1584; i += 256) {                                    \
            int r   = i / 264;                                                     \
            int rem = i - r * 264;                                                 \
            int px  = rem >> 2;                                                    \
            int c8  = rem & 3;                                                     \
            int gy = y0 - 1 + r;                                                   \
            int gx = px0 - 1 + px;                                                 \
            half8 v = {};                                                          \
            if ((unsigned)gy < HH && (unsigned)gx < WW)                            \
                v = *(const half8*)(inp + ((size_t)gy * WW + gx) * CC + c * 32 + c8 * 8); \
            *(half8*)&lds[(r * 66 + px) * PADH + c8 * 8] = v;                      \
        }                                                                          \
        __syncthreads();                                                           \
        _Pragma("unroll") for (int tap = 0; tap < 9; ++tap) {                      \
            int nc   = (tap == 8) ? c + 1 : c;                                     \
            int ntap = (tap == 8) ? 0 : tap + 1;                                   \
            if (nc < 2) {                                                          \
                _Pragma("unroll") for (int o = 0; o < 2; ++o)                      \
                    _Pragma("unroll") for (int il = 0; il < 2; ++il)               \
                        a_nxt[o * 2 + il] = WFRAG(nc, ntap, o, il);                \
            }                                                                      \
            const int dy = tap / 3;                                                \
            const int dx = tap - dy * 3;                                           \
            const _Float16* lbase = &lds[((w + dy) * 66 + dx) * PADH];             \
            _Pragma("unroll") for (int il = 0; il < 2; ++il) {                     \
                const int koff = (il * 2 + ksub) * 8;                              \
                half8 b0 = *(const half8*)(lbase + (n) * PADH + koff);             \
                half8 b1 = *(const half8*)(lbase + (32 + n) * PADH + koff);        \
                acc[0][0] = __builtin_amdgcn_mfma_f32_32x32x16_f16(a_cur[il],     b0, acc[0][0], 0, 0, 0); \
                acc[0][1] = __builtin_amdgcn_mfma_f32_32x32x16_f16(a_cur[il],     b1, acc[0][1], 0, 0, 0); \
                acc[1][0] = __builtin_amdgcn_mfma_f32_32x32x16_f16(a_cur[2 + il], b0, acc[1][0], 0, 0, 0); \
                acc[1][1] = __builtin_amdgcn_mfma_f32_32x32x16_f16(a_cur[2 + il], b1, acc[1][1], 0, 0, 0); \
            }                                                                      \
            _Pragma("unroll") for (int q = 0; q < 4; ++q) a_cur[q] = a_nxt[q];     \
        }                                                                          \
    }

#define WFRAG(c, tap, o, il) \
    (*(const half8*)(Wt + ((((size_t)(tap) * 2 + (c)) * 2 + (il)) * 2 + (o)) * 512 + lane * 8))

// ---------------------------------------------------------------------------
// Conv layers 0..2: bias + ReLU -> NHWC f16
// ---------------------------------------------------------------------------
__global__ __launch_bounds__(256, 4) void conv3x3_mfma(
    const _Float16* __restrict__ in,   // NHWC per task (stride tsi halves)
    _Float16* __restrict__ out,        // NHWC per task (stride tso halves)
    const _Float16* __restrict__ W3,   // [12][36864]
    const float* __restrict__ Bsel,    // [12][64]
    int layer, int task0, size_t tsi, size_t tso)
{
    const int y0  = (blockIdx.x >> 1) * 4;
    const int px0 = (blockIdx.x & 1) * 64;
    const int b   = blockIdx.y;
    const int tz  = blockIdx.z;
    const int t   = task0 + tz;

    const _Float16* inp = in + (size_t)tz * tsi + (size_t)b * (HH * WW * CC);
    _Float16* outp      = out + (size_t)tz * tso + (size_t)b * (HH * WW * CC);
    const int tl = t * LL + layer;
    const _Float16* Wt = W3 + (size_t)tl * 36864;

    const int tid  = threadIdx.x;
    const int lane = tid & 63;
    const int w    = tid >> 6;
    const int n    = lane & 31;
    const int ksub = lane >> 5;

    __shared__ __align__(16) _Float16 lds[6 * 66 * PADH];

    CONV_CORE(inp, Wt)

    const float* Bp = Bsel + tl * CC;
    _Float16* orow = outp + (size_t)(y0 + w) * WW * CC;
#pragma unroll
    for (int o = 0; o < 2; ++o)
#pragma unroll
        for (int j = 0; j < 2; ++j) {
            int px = px0 + j * 32 + n;
            _Float16* po = orow + (size_t)px * CC;
#pragma unroll
            for (int rg = 0; rg < 4; ++rg) {
                int oc = o * 32 + 4 * ksub + 8 * rg;
                half4 h;
#pragma unroll
                for (int k = 0; k < 4; ++k)
                    h[k] = (_Float16)fmaxf(acc[o][j][rg * 4 + k] + Bp[oc + k], 0.f);
                *(half4*)(po + oc) = h;
            }
        }
}

// ---------------------------------------------------------------------------
// Conv layer 3 + fused decoder: relu(conv3) -> 1x1 conv 64->3 (+bias),
// L2-normalize for task 2, write NCHW fp32 output directly.
// Per lane: partial d-sums over its 32 oc; __shfl_xor(32) combines halves.
// ---------------------------------------------------------------------------
__global__ __launch_bounds__(256, 4) void conv3x3_dec(
    const _Float16* __restrict__ in,   // NHWC per task (stride tsi halves)
    float* __restrict__ out,           // [T][B][3][H][W] fp32
    const _Float16* __restrict__ W3,
    const float* __restrict__ Bsel,
    const float* __restrict__ dec_w,   // [T][3][64]
    const float* __restrict__ dec_b,   // [T][3]
    int task0, size_t tsi)
{
    const int y0  = (blockIdx.x >> 1) * 4;
    const int px0 = (blockIdx.x & 1) * 64;
    const int b   = blockIdx.y;
    const int tz  = blockIdx.z;
    const int t   = task0 + tz;

    const _Float16* inp = in + (size_t)tz * tsi + (size_t)b * (HH * WW * CC);
    const int tl = t * LL + 3;
    const _Float16* Wt = W3 + (size_t)tl * 36864;

    const int tid  = threadIdx.x;
    const int lane = tid & 63;
    const int w    = tid >> 6;
    const int n    = lane & 31;
    const int ksub = lane >> 5;

    __shared__ __align__(16) _Float16 lds[6 * 66 * PADH];

    CONV_CORE(inp, Wt)

    const float* Bp  = Bsel + tl * CC;
    const float* dwp = dec_w + (size_t)t * 3 * CC;
    float s[2][3] = {};
#pragma unroll
    for (int o = 0; o < 2; ++o)
#pragma unroll
        for (int rg = 0; rg < 4; ++rg)
#pragma unroll
            for (int k = 0; k < 4; ++k) {
                int oc = o * 32 + 4 * ksub + 8 * rg + k;
                float bb = Bp[oc];
                float w0 = dwp[oc], w1 = dwp[CC + oc], w2 = dwp[2 * CC + oc];
                float v0 = fmaxf(acc[o][0][rg * 4 + k] + bb, 0.f);
                float v1 = fmaxf(acc[o][1][rg * 4 + k] + bb, 0.f);
                s[0][0] += v0 * w0; s[0][1] += v0 * w1; s[0][2] += v0 * w2;
                s[1][0] += v1 * w0; s[1][1] += v1 * w1; s[1][2] += v1 * w2;
            }
#pragma unroll
    for (int j = 0; j < 2; ++j) {
        float s0 = s[j][0], s1 = s[j][1], s2 = s[j][2];
        s0 += __shfl_xor(s0, 32);
        s1 += __shfl_xor(s1, 32);
        s2 += __shfl_xor(s2, 32);
        if (ksub == 0) {
            s0 += dec_b[t * 3 + 0];
            s1 += dec_b[t * 3 + 1];
            s2 += dec_b[t * 3 + 2];
            if (t == 2) {
                float r = 1.0f / sqrtf(s0 * s0 + s1 * s1 + s2 * s2);
                s0 *= r; s1 *= r; s2 *= r;
            }
            int px = px0 + j * 32 + n;
            float* ob = out + (size_t)(t * BB + b) * 3 * (HH * WW)
                            + (size_t)(y0 + w) * WW + px;
            ob[0]           = s0;
            ob[HH * WW]     = s1;
            ob[2 * HH * WW] = s2;
        }
    }
}

extern "C" void kernel_launch(void* const* d_in, const int* in_sizes, int n_in,
                              void* d_out, int out_size, void* d_ws, size_t ws_size,
                              hipStream_t stream) {
    const float* x      = (const float*)d_in[0];
    const float* alpha0 = (const float*)d_in[1];
    const float* alphas = (const float*)d_in[2];
    const float* g0     = (const float*)d_in[3];
    const float* gs     = (const float*)d_in[4];
    const float* enc_w  = (const float*)d_in[5];
    const float* enc_b  = (const float*)d_in[6];
    const float* dec_w  = (const float*)d_in[7];
    const float* dec_b  = (const float*)d_in[8];
    float* out = (float*)d_out;

    const size_t ACT = (size_t)BB * HH * WW * CC;      // halves per activation buffer
    char* pw = (char*)d_ws;
    float* Bsel = (float*)pw;            pw += 4096;
    _Float16* W3 = (_Float16*)pw;        pw += (size_t)12 * 36864 * 2;
    _Float16* act0 = (_Float16*)pw;      pw += ACT * 2;
    _Float16* bufs = (_Float16*)pw;
    size_t base = (size_t)(pw - (char*)d_ws);
    bool fused = ws_size >= base + 6 * ACT * 2;

    prep_weights<<<dim3(36, 12), 256, 0, stream>>>(enc_w, enc_b, alpha0, alphas, g0, gs, W3, Bsel);
    to_nhwc<<<dim3(2, HH, BB), 256, 0, stream>>>(x, act0);

    if (fused) {
        _Float16* A = bufs;        // task stride 2*ACT
        _Float16* B = bufs + ACT;
        size_t ts = 2 * ACT;
        conv3x3_mfma<<<dim3(64, BB, 3), 256, 0, stream>>>(act0, A, W3, Bsel, 0, 0, 0,  ts);
        conv3x3_mfma<<<dim3(64, BB, 3), 256, 0, stream>>>(A,    B, W3, Bsel, 1, 0, ts, ts);
        conv3x3_mfma<<<dim3(64, BB, 3), 256, 0, stream>>>(B,    A, W3, Bsel, 2, 0, ts, ts);
        conv3x3_dec <<<dim3(64, BB, 3), 256, 0, stream>>>(A, out, W3, Bsel, dec_w, dec_b, 0, ts);
    } else {
        _Float16* A = bufs;
        _Float16* B = bufs + ACT;
        for (int t = 0; t < TT; ++t) {
            conv3x3_mfma<<<dim3(64, BB, 1), 256, 0, stream>>>(act0, A, W3, Bsel, 0, t, 0, 0);
            conv3x3_mfma<<<dim3(64, BB, 1), 256, 0, stream>>>(A,    B, W3, Bsel, 1, t, 0, 0);
            conv3x3_mfma<<<dim3(64, BB, 1), 256, 0, stream>>>(B,    A, W3, Bsel, 2, t, 0, 0);
            conv3x3_dec <<<dim3(64, BB, 1), 256, 0, stream>>>(B, out, W3, Bsel, dec_w, dec_b, t, 0);
        }
    }
}